// Round 7
// baseline (118.337 us; speedup 1.0000x reference)
//
#include <hip/hip_runtime.h>
#include <hip/hip_bf16.h>
#include <stdint.h>

#define N_CELLS 196608
#define NH 9
#define F 64            // F_IN == F_OUT == 64
#define K_TOT (NH * F)  // 576
#define K_STEPS (K_TOT / 32)  // 18
#define NFRAG (K_STEPS * 4)   // 72 B-fragments
#define WLDS_SHORTS (NFRAG * 64 * 8)  // 36864 shorts = 72 KB
#define BLOCK 512              // 8 waves, 64 cells per wave

typedef __attribute__((ext_vector_type(8))) short bf16x8;
typedef __attribute__((ext_vector_type(4))) float f32x4;

__device__ inline unsigned short f2bf(float f) {
    union { float f; uint32_t u; } v; v.f = f;
    uint32_t u = v.u;
    uint32_t r = u + 0x7FFFu + ((u >> 16) & 1u);  // round-to-nearest-even
    return (unsigned short)(r >> 16);
}

// ---------------- x: fp32 -> bf16, flat, vectorized -----------------------
__global__ __launch_bounds__(256) void convert_x_kernel(
        const float* __restrict__ x, unsigned short* __restrict__ xb) {
    size_t i = (size_t)blockIdx.x * blockDim.x + threadIdx.x;  // one per 8 elems
    const f32x4* p = reinterpret_cast<const f32x4*>(x);
    f32x4 a = p[i * 2], b = p[i * 2 + 1];
    unsigned short tmp[8];
    #pragma unroll
    for (int j = 0; j < 4; ++j) { tmp[j] = f2bf(a[j]); tmp[4 + j] = f2bf(b[j]); }
    *reinterpret_cast<bf16x8*>(xb + i * 8) = *reinterpret_cast<const bf16x8*>(tmp);
}

// ---------------- W: fp32 [576][64] -> bf16 MFMA B-fragment layout --------
// frag id = kk*4 + t  (kk = K-step 0..17, t = 16-col tile 0..3)
// lane l holds 8 bf16: B[k = kk*32 + (l>>4)*8 + j][o = t*16 + (l&15)]
__global__ __launch_bounds__(256) void convert_w_kernel(
        const float* __restrict__ W, unsigned short* __restrict__ wb) {
    int tid = blockIdx.x * blockDim.x + threadIdx.x;  // 0 .. 4607
    int l = tid & 63;
    int frag = tid >> 6;          // 0..71
    int kk = frag >> 2, t = frag & 3;
    int k0 = kk * 32 + (l >> 4) * 8;
    int o  = t * 16 + (l & 15);
    unsigned short tmp[8];
    #pragma unroll
    for (int j = 0; j < 8; ++j) tmp[j] = f2bf(W[(size_t)(k0 + j) * F + o]);
    *reinterpret_cast<bf16x8*>(wb + (size_t)tid * 8) =
        *reinterpret_cast<const bf16x8*>(tmp);
}

// ---------------- fused gather + GEMM, v7: fenced depth-2 x 16 waves/CU ----
// v6 post-mortem: fences made the depth-2 pipeline real (+7%), but per-CU
// in-flight gather lines (~8 waves x 16) still fall ~2x short of the ~180+
// needed to hide ~600cyc miss latency. v5 post-mortem: 16 waves WITHOUT
// fences regressed (waves stalled serially, only thrashed L2).
// v7 combines them: 512-thread blocks (2 blocks/CU via 72KB LDS = 16
// waves/CU, 4/SIMD) each running the FENCED depth-2 ring. Grid = 384 blocks
// -> all blocks co-resident, no dispatch tail.
template <bool XB>
__global__ __launch_bounds__(BLOCK, 4) void fused_gather_gemm_v7(
        const float* __restrict__ x32, const unsigned short* __restrict__ xb,
        const int* __restrict__ adjc, const unsigned short* __restrict__ wb,
        float* __restrict__ out) {
    __shared__ unsigned short wlds[WLDS_SHORTS];

    const int wave = threadIdx.x >> 6;
    const int lane = threadIdx.x & 63;
    const int lo = lane & 15, hi = lane >> 4;
    const int cellbase = blockIdx.x * BLOCK + wave * 64;

    // --- all neighbor indices up front
    int idx[4][NH];
    #pragma unroll
    for (int m = 0; m < 4; ++m) {
        const int* ap = adjc + (size_t)(cellbase + m * 16 + lo) * NH;
        #pragma unroll
        for (int j = 0; j < NH; ++j) idx[m][j] = __builtin_nontemporal_load(ap + j);
    }

    auto loadA = [&](int m, int j, int h) -> bf16x8 {
        if (XB) {
            return *reinterpret_cast<const bf16x8*>(
                    xb + (size_t)idx[m][j] * F + h * 32 + hi * 8);
        } else {
            const float* ap = x32 + (size_t)idx[m][j] * F + h * 32 + hi * 8;
            f32x4 f0 = *reinterpret_cast<const f32x4*>(ap);
            f32x4 f1 = *reinterpret_cast<const f32x4*>(ap + 4);
            unsigned short tmp[8];
            #pragma unroll
            for (int q = 0; q < 4; ++q) { tmp[q] = f2bf(f0[q]); tmp[4+q] = f2bf(f1[q]); }
            return *reinterpret_cast<const bf16x8*>(tmp);
        }
    };

    // --- stage W into LDS (4608 bf16x8 vectors; 9 per thread, coalesced)
    {
        const bf16x8* src = reinterpret_cast<const bf16x8*>(wb);
        bf16x8* dst = reinterpret_cast<bf16x8*>(wlds);
        #pragma unroll
        for (int it = 0; it < 9; ++it)
            dst[it * BLOCK + threadIdx.x] = src[it * BLOCK + threadIdx.x];
    }

    // --- prologue of the ring: issue A(0), A(1) (complete during W staging)
    bf16x8 aS[3][4][2];
    #pragma unroll
    for (int m = 0; m < 4; ++m)
        #pragma unroll
        for (int h = 0; h < 2; ++h) {
            aS[0][m][h] = loadA(m, 0, h);
            aS[1][m][h] = loadA(m, 1, h);
        }
    __syncthreads();

    f32x4 acc[4][4];
    #pragma unroll
    for (int m = 0; m < 4; ++m)
        #pragma unroll
        for (int t = 0; t < 4; ++t) acc[m][t] = f32x4{0.f, 0.f, 0.f, 0.f};

    #pragma unroll
    for (int j = 0; j < NH; ++j) {
        const int cur = j % 3;            // compile-time after full unroll
        const int nxt = (j + 2) % 3;
        // Issue slice j+2's 16 gathers; the fence below forbids the
        // scheduler from sinking them past this step's MFMAs.
        if (j + 2 < NH) {
            #pragma unroll
            for (int m = 0; m < 4; ++m)
                #pragma unroll
                for (int h = 0; h < 2; ++h) aS[nxt][m][h] = loadA(m, j + 2, h);
        }
        __builtin_amdgcn_sched_barrier(0);   // pin: loads issued above stay above
        #pragma unroll
        for (int h = 0; h < 2; ++h) {
            const int kk = j * 2 + h;
            #pragma unroll
            for (int t = 0; t < 4; ++t) {
                // B from LDS: lane-contiguous 16B -> 2-way bank alias (free)
                bf16x8 b = *reinterpret_cast<const bf16x8*>(
                        &wlds[((size_t)(kk * 4 + t) * 64 + lane) * 8]);
                #pragma unroll
                for (int m = 0; m < 4; ++m)
                    acc[m][t] = __builtin_amdgcn_mfma_f32_16x16x32_bf16(
                            aS[cur][m][h], b, acc[m][t], 0, 0, 0);
            }
        }
        __builtin_amdgcn_sched_barrier(0);   // pin: MFMAs can't float up either
    }

    // C/D layout: col = lane&15, row = (lane>>4)*4 + r   [measured m89/m91]
    #pragma unroll
    for (int m = 0; m < 4; ++m)
        #pragma unroll
        for (int t = 0; t < 4; ++t)
            #pragma unroll
            for (int r = 0; r < 4; ++r) {
                int row = cellbase + m * 16 + hi * 4 + r;
                out[(size_t)row * F + t * 16 + lo] = acc[m][t][r];
            }
}

// ---------------- correctness-only fallback (no workspace) ----------------
__global__ void naive_kernel(const float* __restrict__ x,
                             const int* __restrict__ adjc,
                             const float* __restrict__ W,
                             float* __restrict__ out) {
    int n = blockIdx.x;
    int o = threadIdx.x;  // 64 threads
    float acc = 0.f;
    for (int j = 0; j < NH; ++j) {
        int idx = adjc[(size_t)n * NH + j];
        for (int f = 0; f < F; ++f)
            acc += x[(size_t)idx * F + f] * W[(size_t)(j * F + f) * F + o];
    }
    out[(size_t)n * F + o] = acc;
}

extern "C" void kernel_launch(void* const* d_in, const int* in_sizes, int n_in,
                              void* d_out, int out_size, void* d_ws, size_t ws_size,
                              hipStream_t stream) {
    const float* x    = (const float*)d_in[0];
    const int*   adjc = (const int*)d_in[1];
    const float* W    = (const float*)d_in[2];
    float* out = (float*)d_out;

    const size_t need_x = (size_t)N_CELLS * F * sizeof(unsigned short);  // 25165824
    const size_t need_w = (size_t)K_TOT * F * sizeof(unsigned short);    // 73728

    if (ws_size >= need_x + need_w) {
        unsigned short* xb = (unsigned short*)d_ws;
        unsigned short* wb = (unsigned short*)((char*)d_ws + need_x);
        convert_x_kernel<<<(N_CELLS * F / 8) / 256, 256, 0, stream>>>(x, xb);
        convert_w_kernel<<<(K_STEPS * 4 * 64) / 256, 256, 0, stream>>>(W, wb);
        fused_gather_gemm_v7<true><<<N_CELLS / BLOCK, BLOCK, 0, stream>>>(
                x, xb, adjc, wb, out);
    } else if (ws_size >= need_w) {
        unsigned short* wb = (unsigned short*)d_ws;
        convert_w_kernel<<<(K_STEPS * 4 * 64) / 256, 256, 0, stream>>>(W, wb);
        fused_gather_gemm_v7<false><<<N_CELLS / BLOCK, BLOCK, 0, stream>>>(
                x, nullptr, adjc, wb, out);
    } else {
        naive_kernel<<<N_CELLS, F, 0, stream>>>(x, adjc, W, out);
    }
}

// Round 8
// 62.441 us; speedup vs baseline: 1.8952x; 1.8952x over previous
//
#include <hip/hip_runtime.h>
#include <hip/hip_bf16.h>
#include <stdint.h>

#define N_CELLS 196608
#define NH 9
#define F 64            // F_IN == F_OUT == 64
#define K_TOT (NH * F)  // 576
#define K_STEPS (K_TOT / 32)  // 18
#define NFRAG (K_STEPS * 4)   // 72 B-fragments
#define WLDS_SHORTS (NFRAG * 64 * 8)  // 36864 shorts = 72 KB
#define BLOCK 512              // 8 waves, 32 cells per wave, 256 cells/block

typedef __attribute__((ext_vector_type(8))) short bf16x8;
typedef __attribute__((ext_vector_type(4))) float f32x4;

__device__ inline unsigned short f2bf(float f) {
    union { float f; uint32_t u; } v; v.f = f;
    uint32_t u = v.u;
    uint32_t r = u + 0x7FFFu + ((u >> 16) & 1u);  // round-to-nearest-even
    return (unsigned short)(r >> 16);
}

// ---------------- x: fp32 -> bf16, flat, vectorized -----------------------
__global__ __launch_bounds__(256) void convert_x_kernel(
        const float* __restrict__ x, unsigned short* __restrict__ xb) {
    size_t i = (size_t)blockIdx.x * blockDim.x + threadIdx.x;  // one per 8 elems
    const f32x4* p = reinterpret_cast<const f32x4*>(x);
    f32x4 a = p[i * 2], b = p[i * 2 + 1];
    unsigned short tmp[8];
    #pragma unroll
    for (int j = 0; j < 4; ++j) { tmp[j] = f2bf(a[j]); tmp[4 + j] = f2bf(b[j]); }
    *reinterpret_cast<bf16x8*>(xb + i * 8) = *reinterpret_cast<const bf16x8*>(tmp);
}

// ---------------- W: fp32 [576][64] -> bf16 MFMA B-fragment layout --------
// frag id = kk*4 + t  (kk = K-step 0..17, t = 16-col tile 0..3)
// lane l holds 8 bf16: B[k = kk*32 + (l>>4)*8 + j][o = t*16 + (l&15)]
__global__ __launch_bounds__(256) void convert_w_kernel(
        const float* __restrict__ W, unsigned short* __restrict__ wb) {
    int tid = blockIdx.x * blockDim.x + threadIdx.x;  // 0 .. 4607
    int l = tid & 63;
    int frag = tid >> 6;          // 0..71
    int kk = frag >> 2, t = frag & 3;
    int k0 = kk * 32 + (l >> 4) * 8;
    int o  = t * 16 + (l & 15);
    unsigned short tmp[8];
    #pragma unroll
    for (int j = 0; j < 8; ++j) tmp[j] = f2bf(W[(size_t)(k0 + j) * F + o]);
    *reinterpret_cast<bf16x8*>(wb + (size_t)tid * 8) =
        *reinterpret_cast<const bf16x8*>(tmp);
}

// ---------------- fused gather + GEMM, v8 ----------------------------------
// v7 post-mortem: __launch_bounds__ 2nd arg acts as CUDA min-BLOCKS-per-CU on
// this toolchain (v7: arg=4 with 512 thr -> 32 waves/CU -> 64-VGPR cap ->
// massive spills, WRITE 205MB). v8: (512, 2) -> 16 waves/CU -> 128-VGPR cap,
// and the per-wave footprint is halved (32 cells/wave: acc 32 + ring 48 +
// idx 18 ~= 115 VGPR) so the fenced depth-2 ring fits WITHOUT spilling.
// This finally tests {16 waves/CU} x {real depth-2 pipeline} together.
// Epilogue transposes acc through the (dead) W LDS buffer so every global
// store is 1KB contiguous -- avoids the partial-line write inflation seen
// at high concurrency in v5/v7.
template <bool XB>
__global__ __launch_bounds__(BLOCK, 2) void fused_gather_gemm_v8(
        const float* __restrict__ x32, const unsigned short* __restrict__ xb,
        const int* __restrict__ adjc, const unsigned short* __restrict__ wb,
        float* __restrict__ out) {
    __shared__ unsigned short wlds[WLDS_SHORTS];   // 72 KB

    const int wave = threadIdx.x >> 6;
    const int lane = threadIdx.x & 63;
    const int lo = lane & 15, hi = lane >> 4;
    const int wcell = blockIdx.x * 256 + wave * 32;  // wave's 32 cells

    // --- neighbor indices up front (latency paid once in prologue)
    int idx[2][NH];
    #pragma unroll
    for (int m = 0; m < 2; ++m) {
        const int* ap = adjc + (size_t)(wcell + m * 16 + lo) * NH;
        #pragma unroll
        for (int j = 0; j < NH; ++j) idx[m][j] = __builtin_nontemporal_load(ap + j);
    }

    auto loadA = [&](int m, int j, int h) -> bf16x8 {
        if (XB) {
            return *reinterpret_cast<const bf16x8*>(
                    xb + (size_t)idx[m][j] * F + h * 32 + hi * 8);
        } else {
            const float* ap = x32 + (size_t)idx[m][j] * F + h * 32 + hi * 8;
            f32x4 f0 = *reinterpret_cast<const f32x4*>(ap);
            f32x4 f1 = *reinterpret_cast<const f32x4*>(ap + 4);
            unsigned short tmp[8];
            #pragma unroll
            for (int q = 0; q < 4; ++q) { tmp[q] = f2bf(f0[q]); tmp[4+q] = f2bf(f1[q]); }
            return *reinterpret_cast<const bf16x8*>(tmp);
        }
    };

    // --- stage W into LDS (4608 bf16x8 vectors; 9 per thread, coalesced)
    {
        const bf16x8* src = reinterpret_cast<const bf16x8*>(wb);
        bf16x8* dst = reinterpret_cast<bf16x8*>(wlds);
        #pragma unroll
        for (int it = 0; it < 9; ++it)
            dst[it * BLOCK + threadIdx.x] = src[it * BLOCK + threadIdx.x];
    }

    // --- ring prologue: issue A(0), A(1) (complete during W staging/barrier)
    bf16x8 aS[3][2][2];
    #pragma unroll
    for (int m = 0; m < 2; ++m)
        #pragma unroll
        for (int h = 0; h < 2; ++h) {
            aS[0][m][h] = loadA(m, 0, h);
            aS[1][m][h] = loadA(m, 1, h);
        }
    __syncthreads();

    f32x4 acc[2][4];
    #pragma unroll
    for (int m = 0; m < 2; ++m)
        #pragma unroll
        for (int t = 0; t < 4; ++t) acc[m][t] = f32x4{0.f, 0.f, 0.f, 0.f};

    #pragma unroll
    for (int j = 0; j < NH; ++j) {
        const int cur = j % 3;            // compile-time after full unroll
        const int nxt = (j + 2) % 3;
        // Issue slice j+2's 8 gathers; fence pins them above this step's MFMAs.
        if (j + 2 < NH) {
            #pragma unroll
            for (int m = 0; m < 2; ++m)
                #pragma unroll
                for (int h = 0; h < 2; ++h) aS[nxt][m][h] = loadA(m, j + 2, h);
        }
        __builtin_amdgcn_sched_barrier(0);   // loads issued above stay above
        #pragma unroll
        for (int h = 0; h < 2; ++h) {
            const int kk = j * 2 + h;
            #pragma unroll
            for (int t = 0; t < 4; ++t) {
                // B from LDS: lane-contiguous 16B -> 2-way bank alias (free)
                bf16x8 b = *reinterpret_cast<const bf16x8*>(
                        &wlds[((size_t)(kk * 4 + t) * 64 + lane) * 8]);
                #pragma unroll
                for (int m = 0; m < 2; ++m)
                    acc[m][t] = __builtin_amdgcn_mfma_f32_16x16x32_bf16(
                            aS[cur][m][h], b, acc[m][t], 0, 0, 0);
            }
        }
        __builtin_amdgcn_sched_barrier(0);   // MFMAs can't float up either
    }

    // --- epilogue: transpose through LDS for fully-coalesced 1KB stores ----
    // W buffer is dead; each wave gets a private 2048-float (8KB) region.
    __syncthreads();                       // all waves done reading W
    float* ldsf = reinterpret_cast<float*>(wlds);
    const int rbase = wave * 2048;
    // C/D layout: col = lane&15, row = (lane>>4)*4 + r   [measured m89/m91]
    #pragma unroll
    for (int m = 0; m < 2; ++m)
        #pragma unroll
        for (int t = 0; t < 4; ++t)
            #pragma unroll
            for (int r = 0; r < 4; ++r)
                ldsf[rbase + (m * 16 + hi * 4 + r) * 64 + t * 16 + lo] =
                        acc[m][t][r];
    __syncthreads();                       // writes visible (also wave-local)
    #pragma unroll
    for (int p = 0; p < 8; ++p) {
        const int f = p * 256 + lane * 4;
        f32x4 v = *reinterpret_cast<const f32x4*>(&ldsf[rbase + f]);
        *reinterpret_cast<f32x4*>(&out[(size_t)wcell * F + f]) = v;
    }
}

// ---------------- correctness-only fallback (no workspace) ----------------
__global__ void naive_kernel(const float* __restrict__ x,
                             const int* __restrict__ adjc,
                             const float* __restrict__ W,
                             float* __restrict__ out) {
    int n = blockIdx.x;
    int o = threadIdx.x;  // 64 threads
    float acc = 0.f;
    for (int j = 0; j < NH; ++j) {
        int idx = adjc[(size_t)n * NH + j];
        for (int f = 0; f < F; ++f)
            acc += x[(size_t)idx * F + f] * W[(size_t)(j * F + f) * F + o];
    }
    out[(size_t)n * F + o] = acc;
}

extern "C" void kernel_launch(void* const* d_in, const int* in_sizes, int n_in,
                              void* d_out, int out_size, void* d_ws, size_t ws_size,
                              hipStream_t stream) {
    const float* x    = (const float*)d_in[0];
    const int*   adjc = (const int*)d_in[1];
    const float* W    = (const float*)d_in[2];
    float* out = (float*)d_out;

    const size_t need_x = (size_t)N_CELLS * F * sizeof(unsigned short);  // 25165824
    const size_t need_w = (size_t)K_TOT * F * sizeof(unsigned short);    // 73728

    if (ws_size >= need_x + need_w) {
        unsigned short* xb = (unsigned short*)d_ws;
        unsigned short* wb = (unsigned short*)((char*)d_ws + need_x);
        convert_x_kernel<<<(N_CELLS * F / 8) / 256, 256, 0, stream>>>(x, xb);
        convert_w_kernel<<<(K_STEPS * 4 * 64) / 256, 256, 0, stream>>>(W, wb);
        fused_gather_gemm_v8<true><<<N_CELLS / 256, BLOCK, 0, stream>>>(
                x, xb, adjc, wb, out);
    } else if (ws_size >= need_w) {
        unsigned short* wb = (unsigned short*)d_ws;
        convert_w_kernel<<<(K_STEPS * 4 * 64) / 256, 256, 0, stream>>>(W, wb);
        fused_gather_gemm_v8<false><<<N_CELLS / 256, BLOCK, 0, stream>>>(
                x, nullptr, adjc, wb, out);
    } else {
        naive_kernel<<<N_CELLS, F, 0, stream>>>(x, adjc, W, out);
    }
}